// Round 18
// baseline (247.721 us; speedup 1.0000x reference)
//
#include <hip/hip_runtime.h>
#include <math.h>

#define BSZ 32
#define CCH 192
#define NPIX 784
#define NP 896          // buffer stride (56 groups); only 49 real groups used
#define NGRP 56
#define NGU 49          // 784 = 49 * 16 exactly: no pad candidates
#define OUTC 384
#define KNN 9

typedef short s8v __attribute__((ext_vector_type(8)));
typedef float f4v __attribute__((ext_vector_type(4)));

// ---------------- ws layout ----------------
#define XFH_BYTES ((size_t)BSZ * NGRP * 6 * 64 * 8 * 2)   // 11,010,048
#define XFL_BYTES XFH_BYTES
#define PAIR_BYTES ((size_t)BSZ * NP * 8)                 //    229,376
#define IDX_BYTES ((size_t)BSZ * NPIX * KNN * 4)          //    903,168
#define TBUF_BYTES ((size_t)BSZ * 192 * NPIX * 4)         // 19,267,584
#define WF_BYTES ((size_t)24 * 3 * 64 * 8 * 2)            //     73,728 per buffer

__device__ __forceinline__ ushort bf16_rne(float f) {
    uint u = __float_as_uint(f);
    uint r = (u + 0x7fffu + ((u >> 16) & 1u)) >> 16;
    return (ushort)r;
}
__device__ __forceinline__ float bf16f(ushort h) { return __uint_as_float(((uint)h) << 16); }

// Abramowitz-Stegun 7.1.26 erf (|eps| <= 1.5e-7) -> exact-gelu within fp32 noise
__device__ __forceinline__ float gelu_fast(float u) {
    float x = u * 0.70710678118654752440f;
    float ax = fabsf(x);
    float t = __builtin_amdgcn_rcpf(fmaf(0.3275911f, ax, 1.0f));
    float p = t * fmaf(t, fmaf(t, fmaf(t, fmaf(t, 1.061405429f, -1.453152027f),
                                       1.421413741f), -0.284496736f), 0.254829592f);
    float e = __expf(-ax * ax);
    float erf_ax = fmaf(-p, e, 1.0f);
    float erfx = copysignf(erf_ax, x);
    return 0.5f * u * (1.0f + erfx);
}

// ---------------- K0: W -> bf16 hi/lo MFMA B-fragments (once). W rows = 96 ch = 3 kc chunks ----------------
__global__ __launch_bounds__(64) void k0_wfrag(const float* __restrict__ w,
                                               ushort* __restrict__ wfh,
                                               ushort* __restrict__ wfl) {
    int c2 = blockIdx.x;        // 0..71 : ob(24) * 3 + kc
    int l = threadIdx.x;
    int ob = c2 / 3, kc = c2 - ob * 3;
    int row = ob * 16 + (l & 15);
    int k0c = kc * 32 + (l >> 4) * 8;          // 0..95: within-row channel index
    const float* wr = w + row * 96 + k0c;
    s8v hv, lv;
#pragma unroll
    for (int k = 0; k < 8; ++k) {
        float v = wr[k];
        ushort h = bf16_rne(v);
        hv[k] = (short)h;
        lv[k] = (short)bf16_rne(v - bf16f(h));
    }
    *(s8v*)(wfh + ((size_t)c2 * 64 + l) * 8) = hv;
    *(s8v*)(wfl + ((size_t)c2 * 64 + l) * 8) = lv;
}

// ---------------- K1: coalesced load -> RAW bf16 hi/lo fragments + {sq,inv} ----------------
__global__ __launch_bounds__(256) void k1_normalize(const float* __restrict__ x,
                                                    ushort* __restrict__ xfh,
                                                    ushort* __restrict__ xfl,
                                                    float2* __restrict__ pair) {
    __shared__ float xs[CCH][65];
    int b = blockIdx.y;
    int n0 = blockIdx.x * 64;
    int t = threadIdx.x;
    const float* xb = x + (size_t)b * CCH * NPIX;

    for (int i = t; i < CCH * 64; i += 256) {
        int c = i >> 6, j = i & 63, n = n0 + j;
        xs[c][j] = (n < NPIX) ? xb[c * NPIX + n] : 0.f;
    }
    __syncthreads();

    {
        int j = t >> 2, part = t & 3;
        float ss = 0.f;
        for (int k = 0; k < 48; ++k) { float v = xs[part * 48 + k][j]; ss = fmaf(v, v, ss); }
        ss += __shfl_xor(ss, 1);
        ss += __shfl_xor(ss, 2);
        float inv = 1.0f / fmaxf(sqrtf(ss), 1e-12f);
        float s2 = 0.f;
        for (int k = 0; k < 48; ++k) {
            float v = xs[part * 48 + k][j] * inv;
            s2 = fmaf(v, v, s2);
        }
        s2 += __shfl_xor(s2, 1);
        s2 += __shfl_xor(s2, 2);
        if (part == 0) {
            int n = n0 + j;
            pair[b * NP + n] = (n < NPIX) ? make_float2(s2, inv) : make_float2(1e30f, 0.f);
        }
    }

#pragma unroll
    for (int i = 0; i < 6; ++i) {
        int ch = t + i * 256;
        int g = ch / 384, rem = ch - g * 384;
        int kc = rem >> 6, l = rem & 63;
        int nl = g * 16 + (l & 15);
        int c0 = kc * 32 + (l >> 4) * 8;
        s8v hv, lv;
#pragma unroll
        for (int k = 0; k < 8; ++k) {
            float v = xs[c0 + k][nl];
            ushort h = bf16_rne(v);
            hv[k] = (short)h;
            lv[k] = (short)bf16_rne(v - bf16f(h));
        }
        size_t doff = (((size_t)(b * NGRP + (n0 >> 4) + g)) * 6 + kc) * 512 + (size_t)l * 8;
        *(s8v*)(xfh + doff) = hv;
        *(s8v*)(xfl + doff) = lv;
    }
}

// ---------------- K2: MFMA knn, 2 query groups/block share the candidate stream ----------------
__device__ __forceinline__ bool lt_pair(float v, int id, float dv, int di) {
    return (v < dv) || (v == dv && id < di);
}
// branchless strict-< sorted insert (ascending per-lane id stream -> lax.top_k tie order)
__device__ __forceinline__ void ins9b(float (&d)[KNN], int (&ii)[KNN], float v, int id) {
    bool c[KNN];
#pragma unroll
    for (int p = 0; p < KNN; ++p) c[p] = v < d[p];
    float nd[KNN]; int ni[KNN];
    nd[0] = c[0] ? v : d[0];
    ni[0] = c[0] ? id : ii[0];
#pragma unroll
    for (int p = 1; p < KNN; ++p) {
        nd[p] = c[p - 1] ? d[p - 1] : (c[p] ? v : d[p]);
        ni[p] = c[p - 1] ? ii[p - 1] : (c[p] ? id : ii[p]);
    }
#pragma unroll
    for (int p = 0; p < KNN; ++p) { d[p] = nd[p]; ii[p] = ni[p]; }
}

__global__ __launch_bounds__(256, 3) void k2_knn(const ushort* __restrict__ xfh,
                                                 const ushort* __restrict__ xfl,
                                                 const float* __restrict__ pair,
                                                 int* __restrict__ nnidx) {
    __shared__ ushort qlds[2][6144];           // 24 KB: [qg][half*3072 + chunk]
    __shared__ float dls[4][64][KNN];          //  9,216 B (merge, reused per qg)
    __shared__ int   ils[4][64][KNN];          //  9,216 B
    int wg = blockIdx.x;                       // 800 = 8 xcd * (4 b * 25 qp)
    int b  = (wg & 7) * 4 + (wg >> 3) / 25;
    int qp = (wg >> 3) % 25;
    int qt0 = qp * 2;
    int qt1 = (qp * 2 + 1 > 48) ? 48 : qp * 2 + 1;   // qp=24 duplicates qt48 (benign)
    int t = threadIdx.x, w = t >> 6, l = t & 63;
    int lk = l >> 4;
    const ushort* fh = xfh + (size_t)b * NGRP * 3072;
    const ushort* fl = xfl + (size_t)b * NGRP * 3072;
    const float2* pb = (const float2*)(pair + (size_t)b * NP * 2);
    int l8 = l * 8;

    // stage both query groups into LDS (2 x 12 KB)
    for (int i = t; i < 1536; i += 256) {
        int qg = i / 768, rem = i - qg * 768;
        int half = rem / 384, off = (rem - half * 384) * 8;
        int qtg = qg ? qt1 : qt0;
        s8v v = *(const s8v*)((half ? fl : fh) + (size_t)qtg * 3072 + off);
        *(s8v*)(&qlds[qg][half * 3072 + off]) = v;
    }
    float c2qA = -2.f * pb[qt0 * 16 + (l & 15)].y;
    float c2qB = -2.f * pb[qt1 * 16 + (l & 15)].y;
    __syncthreads();

    float d9A[KNN], d9B[KNN]; int i9A[KNN], i9B[KNN];
#pragma unroll
    for (int r = 0; r < KNN; ++r) {
        d9A[r] = 3.4e38f; i9A[r] = 0x7fffffff;
        d9B[r] = 3.4e38f; i9B[r] = 0x7fffffff;
    }

    const ushort* qpA = &qlds[0][0] + l8;
    const ushort* qpB = &qlds[1][0] + l8;

    // 4-way candidate split: w0 [0,13), w1 [13,25), w2 [25,37), w3 [37,49)
    int g0 = (w == 0) ? 0 : 13 + (w - 1) * 12;
    int g1 = (w == 0) ? 13 : g0 + 12;
    for (int cg = g0; cg < g1; ++cg) {
        const ushort* ch = fh + (size_t)cg * 3072 + l8;
        const ushort* cl = fl + (size_t)cg * 3072 + l8;
        f4v aH0  = {0.f, 0.f, 0.f, 0.f}, aX10 = {0.f, 0.f, 0.f, 0.f};
        f4v aX20 = {0.f, 0.f, 0.f, 0.f}, aX30 = {0.f, 0.f, 0.f, 0.f};
        f4v aH1  = {0.f, 0.f, 0.f, 0.f}, aX11 = {0.f, 0.f, 0.f, 0.f};
        f4v aX21 = {0.f, 0.f, 0.f, 0.f}, aX31 = {0.f, 0.f, 0.f, 0.f};
#pragma unroll
        for (int kc = 0; kc < 6; ++kc) {
            s8v vh = *(const s8v*)(ch + kc * 512);
            s8v vl = *(const s8v*)(cl + kc * 512);
            s8v qhA = *(const s8v*)(qpA + kc * 512);
            s8v qlA = *(const s8v*)(qpA + 3072 + kc * 512);
            s8v qhB = *(const s8v*)(qpB + kc * 512);
            s8v qlB = *(const s8v*)(qpB + 3072 + kc * 512);
            aH0  = __builtin_amdgcn_mfma_f32_16x16x32_bf16(vh, qhA, aH0,  0, 0, 0);
            aX10 = __builtin_amdgcn_mfma_f32_16x16x32_bf16(vl, qhA, aX10, 0, 0, 0);
            aX20 = __builtin_amdgcn_mfma_f32_16x16x32_bf16(vh, qlA, aX20, 0, 0, 0);
            aX30 = __builtin_amdgcn_mfma_f32_16x16x32_bf16(vl, qlA, aX30, 0, 0, 0);
            aH1  = __builtin_amdgcn_mfma_f32_16x16x32_bf16(vh, qhB, aH1,  0, 0, 0);
            aX11 = __builtin_amdgcn_mfma_f32_16x16x32_bf16(vl, qhB, aX11, 0, 0, 0);
            aX21 = __builtin_amdgcn_mfma_f32_16x16x32_bf16(vh, qlB, aX21, 0, 0, 0);
            aX31 = __builtin_amdgcn_mfma_f32_16x16x32_bf16(vl, qlB, aX31, 0, 0, 0);
        }
        float4 pA4 = *(const float4*)(pb + (size_t)(cg * 16 + lk * 4));
        float4 pB4 = *(const float4*)(pb + (size_t)(cg * 16 + lk * 4) + 2);
        float sqn_[4] = {pA4.x, pA4.z, pB4.x, pB4.z};
        float inv_[4] = {pA4.y, pA4.w, pB4.y, pB4.w};
#pragma unroll
        for (int r = 0; r < 4; ++r) {
            int id = cg * 16 + lk * 4 + r;
            float vA = fmaf(c2qA * inv_[r], aH0[r] + aX10[r] + aX20[r] + aX30[r], sqn_[r]);
            ins9b(d9A, i9A, vA, id);
            float vB = fmaf(c2qB * inv_[r], aH1[r] + aX11[r] + aX21[r] + aX31[r], sqn_[r]);
            ins9b(d9B, i9B, vB, id);
        }
    }

    // merge qg0 (16 sorted lists), then qg1, reusing the same LDS region
#pragma unroll
    for (int r = 0; r < KNN; ++r) { dls[w][l][r] = d9A[r]; ils[w][l][r] = i9A[r]; }
    __syncthreads();
    if (t < 16) {
        int q = qt0 * 16 + t;
        int pk[16];
#pragma unroll
        for (int m = 0; m < 16; ++m) pk[m] = 0;
        int* op = nnidx + ((size_t)b * NPIX + q) * KNN;
        for (int r = 0; r < KNN; ++r) {
            float best = 3.4e38f; int bi = 0x7fffffff; int bk = 0;
#pragma unroll
            for (int m = 0; m < 16; ++m) {
                int ww = m >> 2, kk = m & 3;
                int idx = pk[m] < KNN ? pk[m] : KNN - 1;
                float v = dls[ww][kk * 16 + t][idx];
                int ii = ils[ww][kk * 16 + t][idx];
                if (pk[m] < KNN && lt_pair(v, ii, best, bi)) { best = v; bi = ii; bk = m; }
            }
            op[r] = bi;
#pragma unroll
            for (int m = 0; m < 16; ++m) pk[m] += (m == bk) ? 1 : 0;
        }
    }
    __syncthreads();
#pragma unroll
    for (int r = 0; r < KNN; ++r) { dls[w][l][r] = d9B[r]; ils[w][l][r] = i9B[r]; }
    __syncthreads();
    if (t < 16) {
        int q = qt1 * 16 + t;
        int pk[16];
#pragma unroll
        for (int m = 0; m < 16; ++m) pk[m] = 0;
        int* op = nnidx + ((size_t)b * NPIX + q) * KNN;
        for (int r = 0; r < KNN; ++r) {
            float best = 3.4e38f; int bi = 0x7fffffff; int bk = 0;
#pragma unroll
            for (int m = 0; m < 16; ++m) {
                int ww = m >> 2, kk = m & 3;
                int idx = pk[m] < KNN ? pk[m] : KNN - 1;
                float v = dls[ww][kk * 16 + t][idx];
                int ii = ils[ww][kk * 16 + t][idx];
                if (pk[m] < KNN && lt_pair(v, ii, best, bi)) { best = v; bi = ii; bk = m; }
            }
            op[r] = bi;
#pragma unroll
            for (int m = 0; m < 16; ++m) pk[m] += (m == bk) ? 1 : 0;
        }
    }
}

// ---------------- K3: MFMA projection with precomputed W fragments ----------------
__global__ __launch_bounds__(256, 2) void k3_proj(const ushort* __restrict__ xfh,
                                                  const ushort* __restrict__ xfl,
                                                  const ushort* __restrict__ wfh,
                                                  const ushort* __restrict__ wfl,
                                                  const float* __restrict__ bias,
                                                  float* __restrict__ out,
                                                  float* __restrict__ tbuf) {
    int wg = blockIdx.x;                       // 1568 = 8 xcd * (4 b * 49 ng)
    int b  = (wg & 7) * 4 + (wg >> 3) / 49;
    int ng = (wg >> 3) % 49;
    int t = threadIdx.x, g = t >> 6, l = t & 63;
    int h = l >> 4, m16 = l & 15;
    int kb = (g & 1) * 3;                      // X-side channel-half selector ONLY
    int l8 = l * 8;

    const ushort* fh = xfh + (((size_t)(b * NGRP + ng)) * 6 + kb) * 512 + l8;
    const ushort* fl = xfl + (((size_t)(b * NGRP + ng)) * 6 + kb) * 512 + l8;
    s8v xh[3], xl[3];
#pragma unroll
    for (int kk = 0; kk < 3; ++kk) {
        xh[kk] = *(const s8v*)(fh + kk * 512);
        xl[kk] = *(const s8v*)(fl + kk * 512);
    }

    for (int ogg = 0; ogg < 6; ++ogg) {
        int ob = g * 6 + ogg;                  // og_block: rows ob*16..+15
        const ushort* ph = wfh + ((size_t)ob * 3) * 512 + l8;   // W k-dim is 0..95 always
        const ushort* pl = wfl + ((size_t)ob * 3) * 512 + l8;
        f4v acc = {0.f, 0.f, 0.f, 0.f};
#pragma unroll
        for (int kk = 0; kk < 3; ++kk) {
            s8v wh = *(const s8v*)(ph + kk * 512);
            s8v wl = *(const s8v*)(pl + kk * 512);
            acc = __builtin_amdgcn_mfma_f32_16x16x32_bf16(xh[kk], wh, acc, 0, 0, 0);
            acc = __builtin_amdgcn_mfma_f32_16x16x32_bf16(xh[kk], wl, acc, 0, 0, 0);
            acc = __builtin_amdgcn_mfma_f32_16x16x32_bf16(xl[kk], wh, acc, 0, 0, 0);
        }
        int row = g * 96 + ogg * 16 + m16;
        if (g < 2) {
            float bv = bias[row];
#pragma unroll
            for (int r = 0; r < 4; ++r) {
                int n = ng * 16 + h * 4 + r;
                out[((size_t)b * OUTC + row) * NPIX + n] = gelu_fast(acc[r] + bv);
            }
        } else {
            int r2 = (g - 2) * 96 + ogg * 16 + m16;
#pragma unroll
            for (int r = 0; r < 4; ++r) {
                int n = ng * 16 + h * 4 + r;
                tbuf[((size_t)b * 192 + r2) * NPIX + n] = acc[r];
            }
        }
    }
}

// ---------------- K4: groups 2/3, 8 channels per block (nnidx staged once) ----------------
// gelu unimodal: max over set = max(gelu(umin), gelu(umax))
__global__ __launch_bounds__(256) void k4_gather(const float* __restrict__ tbuf,
                                                 const int* __restrict__ nnidx,
                                                 const float* __restrict__ bias,
                                                 float* __restrict__ out) {
    __shared__ float trow[NPIX];
    __shared__ int nn[NPIX * KNN];
    int wg = blockIdx.x;                       // 768 = 8 xcd * (4 b * 24 oct)
    int b   = (wg & 7) * 4 + (wg >> 3) / 24;
    int oct = (wg >> 3) % 24;
    int t = threadIdx.x;
    const int4* nb4 = (const int4*)(nnidx + (size_t)b * NPIX * KNN);
    for (int i = t; i < NPIX * KNN / 4; i += 256) ((int4*)nn)[i] = nb4[i];

    for (int oo = 0; oo < 8; ++oo) {
        int og2 = oct * 8 + oo;
        const float4* tr4 = (const float4*)(tbuf + ((size_t)b * 192 + og2) * NPIX);
        for (int i = t; i < NPIX / 4; i += 256) ((float4*)trow)[i] = tr4[i];
        __syncthreads();
        float bv = bias[192 + og2];
        float* orow = out + ((size_t)b * OUTC + 192 + og2) * NPIX;
        for (int n = t; n < NPIX; n += 256) {
            float ti = trow[n];
            const int* ip = nn + n * KNN;
            float umin = 3.4e38f, umax = -3.4e38f;
#pragma unroll
            for (int k = 0; k < KNN; ++k) {
                int j = ip[k];
                float u = trow[j] - ti + bv;
                umin = fminf(umin, u);
                umax = fmaxf(umax, u);
            }
            orow[n] = fmaxf(gelu_fast(umin), gelu_fast(umax));
        }
        __syncthreads();                       // before next trow overwrite
    }
}

extern "C" void kernel_launch(void* const* d_in, const int* in_sizes, int n_in,
                              void* d_out, int out_size, void* d_ws, size_t ws_size,
                              hipStream_t stream) {
    const float* x    = (const float*)d_in[0];
    const float* w    = (const float*)d_in[1];
    const float* bias = (const float*)d_in[2];
    float* out = (float*)d_out;
    char* ws = (char*)d_ws;

    ushort* xfh   = (ushort*)(ws);
    ushort* xfl   = (ushort*)(ws + XFH_BYTES);
    float2* pair  = (float2*)(ws + XFH_BYTES + XFL_BYTES);
    int*    nnidx = (int*)   (ws + XFH_BYTES + XFL_BYTES + PAIR_BYTES);
    float*  tbuf  = (float*) (ws + XFH_BYTES + XFL_BYTES + PAIR_BYTES + IDX_BYTES);
    ushort* wfh   = (ushort*)(ws + XFH_BYTES + XFL_BYTES + PAIR_BYTES + IDX_BYTES + TBUF_BYTES);
    ushort* wfl   = (ushort*)(ws + XFH_BYTES + XFL_BYTES + PAIR_BYTES + IDX_BYTES + TBUF_BYTES + WF_BYTES);

    k0_wfrag<<<dim3(72), 64, 0, stream>>>(w, wfh, wfl);
    k1_normalize<<<dim3(13, BSZ), 256, 0, stream>>>(x, xfh, xfl, pair);
    k2_knn<<<dim3(800), 256, 0, stream>>>(xfh, xfl, (const float*)pair, nnidx);
    k3_proj<<<dim3(1568), 256, 0, stream>>>(xfh, xfl, wfh, wfl, bias, out, tbuf);
    k4_gather<<<dim3(768), 256, 0, stream>>>(tbuf, nnidx, bias, out);
}

// Round 19
// 133.501 us; speedup vs baseline: 1.8556x; 1.8556x over previous
//
#include <hip/hip_runtime.h>
#include <math.h>

#define BSZ 32
#define CCH 192
#define NPIX 784
#define NP 896          // buffer stride (56 groups); only 49 real groups used
#define NGRP 56
#define NGU 49          // 784 = 49 * 16 exactly: no pad candidates
#define OUTC 384
#define KNN 9

typedef short s8v __attribute__((ext_vector_type(8)));
typedef float f4v __attribute__((ext_vector_type(4)));

// ---------------- ws layout ----------------
#define XFH_BYTES ((size_t)BSZ * NGRP * 6 * 64 * 8 * 2)   // 11,010,048
#define XFL_BYTES XFH_BYTES
#define PAIR_BYTES ((size_t)BSZ * NP * 8)                 //    229,376
#define IDX_BYTES ((size_t)BSZ * NPIX * KNN * 4)          //    903,168
#define TBUF_BYTES ((size_t)BSZ * 192 * NPIX * 4)         // 19,267,584
#define WF_BYTES ((size_t)24 * 3 * 64 * 8 * 2)            //     73,728 per buffer

__device__ __forceinline__ ushort bf16_rne(float f) {
    uint u = __float_as_uint(f);
    uint r = (u + 0x7fffu + ((u >> 16) & 1u)) >> 16;
    return (ushort)r;
}
__device__ __forceinline__ float bf16f(ushort h) { return __uint_as_float(((uint)h) << 16); }

// Abramowitz-Stegun 7.1.26 erf (|eps| <= 1.5e-7) -> exact-gelu within fp32 noise
__device__ __forceinline__ float gelu_fast(float u) {
    float x = u * 0.70710678118654752440f;
    float ax = fabsf(x);
    float t = __builtin_amdgcn_rcpf(fmaf(0.3275911f, ax, 1.0f));
    float p = t * fmaf(t, fmaf(t, fmaf(t, fmaf(t, 1.061405429f, -1.453152027f),
                                       1.421413741f), -0.284496736f), 0.254829592f);
    float e = __expf(-ax * ax);
    float erf_ax = fmaf(-p, e, 1.0f);
    float erfx = copysignf(erf_ax, x);
    return 0.5f * u * (1.0f + erfx);
}

// ---------------- K0: W -> bf16 hi/lo MFMA B-fragments (once). W rows = 96 ch = 3 kc chunks ----------------
__global__ __launch_bounds__(64) void k0_wfrag(const float* __restrict__ w,
                                               ushort* __restrict__ wfh,
                                               ushort* __restrict__ wfl) {
    int c2 = blockIdx.x;        // 0..71 : ob(24) * 3 + kc
    int l = threadIdx.x;
    int ob = c2 / 3, kc = c2 - ob * 3;
    int row = ob * 16 + (l & 15);
    int k0c = kc * 32 + (l >> 4) * 8;          // 0..95: within-row channel index
    const float* wr = w + row * 96 + k0c;
    s8v hv, lv;
#pragma unroll
    for (int k = 0; k < 8; ++k) {
        float v = wr[k];
        ushort h = bf16_rne(v);
        hv[k] = (short)h;
        lv[k] = (short)bf16_rne(v - bf16f(h));
    }
    *(s8v*)(wfh + ((size_t)c2 * 64 + l) * 8) = hv;
    *(s8v*)(wfl + ((size_t)c2 * 64 + l) * 8) = lv;
}

// ---------------- K1: coalesced load -> RAW bf16 hi/lo fragments + {sq,inv} ----------------
__global__ __launch_bounds__(256) void k1_normalize(const float* __restrict__ x,
                                                    ushort* __restrict__ xfh,
                                                    ushort* __restrict__ xfl,
                                                    float2* __restrict__ pair) {
    __shared__ float xs[CCH][65];
    int b = blockIdx.y;
    int n0 = blockIdx.x * 64;
    int t = threadIdx.x;
    const float* xb = x + (size_t)b * CCH * NPIX;

    for (int i = t; i < CCH * 64; i += 256) {
        int c = i >> 6, j = i & 63, n = n0 + j;
        xs[c][j] = (n < NPIX) ? xb[c * NPIX + n] : 0.f;
    }
    __syncthreads();

    {
        int j = t >> 2, part = t & 3;
        float ss = 0.f;
        for (int k = 0; k < 48; ++k) { float v = xs[part * 48 + k][j]; ss = fmaf(v, v, ss); }
        ss += __shfl_xor(ss, 1);
        ss += __shfl_xor(ss, 2);
        float inv = 1.0f / fmaxf(sqrtf(ss), 1e-12f);
        float s2 = 0.f;
        for (int k = 0; k < 48; ++k) {
            float v = xs[part * 48 + k][j] * inv;
            s2 = fmaf(v, v, s2);
        }
        s2 += __shfl_xor(s2, 1);
        s2 += __shfl_xor(s2, 2);
        if (part == 0) {
            int n = n0 + j;
            pair[b * NP + n] = (n < NPIX) ? make_float2(s2, inv) : make_float2(1e30f, 0.f);
        }
    }

#pragma unroll
    for (int i = 0; i < 6; ++i) {
        int ch = t + i * 256;
        int g = ch / 384, rem = ch - g * 384;
        int kc = rem >> 6, l = rem & 63;
        int nl = g * 16 + (l & 15);
        int c0 = kc * 32 + (l >> 4) * 8;
        s8v hv, lv;
#pragma unroll
        for (int k = 0; k < 8; ++k) {
            float v = xs[c0 + k][nl];
            ushort h = bf16_rne(v);
            hv[k] = (short)h;
            lv[k] = (short)bf16_rne(v - bf16f(h));
        }
        size_t doff = (((size_t)(b * NGRP + (n0 >> 4) + g)) * 6 + kc) * 512 + (size_t)l * 8;
        *(s8v*)(xfh + doff) = hv;
        *(s8v*)(xfl + doff) = lv;
    }
}

// ---------------- K2: MFMA knn, queries served from LDS (off the TCP port) ----------------
__device__ __forceinline__ bool lt_pair(float v, int id, float dv, int di) {
    return (v < dv) || (v == dv && id < di);
}
// branchless strict-< sorted insert (ascending per-lane id stream -> lax.top_k tie order)
__device__ __forceinline__ void ins9b(float (&d)[KNN], int (&ii)[KNN], float v, int id) {
    bool c[KNN];
#pragma unroll
    for (int p = 0; p < KNN; ++p) c[p] = v < d[p];
    float nd[KNN]; int ni[KNN];
    nd[0] = c[0] ? v : d[0];
    ni[0] = c[0] ? id : ii[0];
#pragma unroll
    for (int p = 1; p < KNN; ++p) {
        nd[p] = c[p - 1] ? d[p - 1] : (c[p] ? v : d[p]);
        ni[p] = c[p - 1] ? ii[p - 1] : (c[p] ? id : ii[p]);
    }
#pragma unroll
    for (int p = 0; p < KNN; ++p) { d[p] = nd[p]; ii[p] = ni[p]; }
}

__global__ __launch_bounds__(128) void k2_knn(const ushort* __restrict__ xfh,
                                              const ushort* __restrict__ xfl,
                                              const float* __restrict__ pair,
                                              int* __restrict__ nnidx) {
    __shared__ ushort qlds[12 * 512];          // 12 KB: chunks 0..5 = hi, 6..11 = lo
    __shared__ float dls[2][64][KNN];
    __shared__ int   ils[2][64][KNN];
    int wg = blockIdx.x;                       // 1568 = 8 xcd * (4 b * 49 qt)
    int b  = (wg & 7) * 4 + (wg >> 3) / 49;
    int qt = (wg >> 3) % 49;
    int t = threadIdx.x, w = t >> 6, l = t & 63;
    int lk = l >> 4;
    const ushort* fh = xfh + (size_t)b * NGRP * 3072;
    const ushort* fl = xfl + (size_t)b * NGRP * 3072;
    const float2* pb = (const float2*)(pair + (size_t)b * NP * 2);
    int l8 = l * 8;

    // stage query fragments (16 queries of group qt) into LDS once
    {
        const ushort* qh_g = fh + (size_t)qt * 3072;
        const ushort* ql_g = fl + (size_t)qt * 3072;
        for (int i = t; i < 768; i += 128) {   // 768 chunks of 8 ushorts = 12 KB
            int half = i / 384;
            int off = (i - half * 384) * 8;
            s8v v = *(const s8v*)((half ? ql_g : qh_g) + off);
            *(s8v*)(qlds + half * 3072 + off) = v;
        }
    }
    float c2q = -2.f * pb[qt * 16 + (l & 15)].y;
    __syncthreads();

    float d9[KNN]; int i9[KNN];
#pragma unroll
    for (int r = 0; r < KNN; ++r) { d9[r] = 3.4e38f; i9[r] = 0x7fffffff; }

    const ushort* qp = qlds + l8;              // per-lane LDS base; kc via imm offsets

    // wave 0: groups 0..23, wave 1: groups 24..48 (784 real candidates, no pads)
    int g0 = w ? 24 : 0, g1 = w ? NGU : 24;
#pragma unroll 2
    for (int cg = g0; cg < g1; ++cg) {
        const ushort* ch = fh + (size_t)cg * 3072 + l8;
        const ushort* cl = fl + (size_t)cg * 3072 + l8;
        f4v aH  = {0.f, 0.f, 0.f, 0.f};
        f4v aX1 = {0.f, 0.f, 0.f, 0.f};
        f4v aX2 = {0.f, 0.f, 0.f, 0.f};
        f4v aX3 = {0.f, 0.f, 0.f, 0.f};
#pragma unroll
        for (int kc = 0; kc < 6; ++kc) {
            s8v vh = *(const s8v*)(ch + kc * 512);
            s8v vl = *(const s8v*)(cl + kc * 512);
            s8v qh = *(const s8v*)(qp + kc * 512);          // ds_read_b128
            s8v ql = *(const s8v*)(qp + 3072 + kc * 512);   // ds_read_b128
            aH  = __builtin_amdgcn_mfma_f32_16x16x32_bf16(vh, qh, aH,  0, 0, 0);
            aX1 = __builtin_amdgcn_mfma_f32_16x16x32_bf16(vl, qh, aX1, 0, 0, 0);
            aX2 = __builtin_amdgcn_mfma_f32_16x16x32_bf16(vh, ql, aX2, 0, 0, 0);
            aX3 = __builtin_amdgcn_mfma_f32_16x16x32_bf16(vl, ql, aX3, 0, 0, 0);
        }
        float4 pA = *(const float4*)(pb + (size_t)(cg * 16 + lk * 4));
        float4 pB = *(const float4*)(pb + (size_t)(cg * 16 + lk * 4) + 2);
        float sqn_[4] = {pA.x, pA.z, pB.x, pB.z};
        float inv_[4] = {pA.y, pA.w, pB.y, pB.w};
#pragma unroll
        for (int r = 0; r < 4; ++r) {
            float v = fmaf(c2q * inv_[r], aH[r] + aX1[r] + aX2[r] + aX3[r], sqn_[r]);
            ins9b(d9, i9, v, cg * 16 + lk * 4 + r);
        }
    }

    // dump 8 sorted lists per query (2 waves x 4 lk-groups) and merge
#pragma unroll
    for (int r = 0; r < KNN; ++r) { dls[w][l][r] = d9[r]; ils[w][l][r] = i9[r]; }
    __syncthreads();
    if (t < 16) {
        int q = qt * 16 + t;
        int pk[8] = {0, 0, 0, 0, 0, 0, 0, 0};
        int* op = nnidx + ((size_t)b * NPIX + q) * KNN;
        for (int r = 0; r < KNN; ++r) {
            float best = 3.4e38f; int bi = 0x7fffffff; int bk = 0;
#pragma unroll
            for (int m = 0; m < 8; ++m) {
                int ww = m >> 2, kk = m & 3;
                int idx = pk[m] < KNN ? pk[m] : KNN - 1;
                float v = dls[ww][kk * 16 + t][idx];
                int ii = ils[ww][kk * 16 + t][idx];
                if (pk[m] < KNN && lt_pair(v, ii, best, bi)) { best = v; bi = ii; bk = m; }
            }
            op[r] = bi;
#pragma unroll
            for (int m = 0; m < 8; ++m) pk[m] += (m == bk) ? 1 : 0;
        }
    }
}

// ---------------- K3: MFMA projection with precomputed W fragments ----------------
__global__ __launch_bounds__(256, 2) void k3_proj(const ushort* __restrict__ xfh,
                                                  const ushort* __restrict__ xfl,
                                                  const ushort* __restrict__ wfh,
                                                  const ushort* __restrict__ wfl,
                                                  const float* __restrict__ bias,
                                                  float* __restrict__ out,
                                                  float* __restrict__ tbuf) {
    int wg = blockIdx.x;                       // 1568 = 8 xcd * (4 b * 49 ng)
    int b  = (wg & 7) * 4 + (wg >> 3) / 49;
    int ng = (wg >> 3) % 49;
    int t = threadIdx.x, g = t >> 6, l = t & 63;
    int h = l >> 4, m16 = l & 15;
    int kb = (g & 1) * 3;                      // X-side channel-half selector ONLY
    int l8 = l * 8;

    const ushort* fh = xfh + (((size_t)(b * NGRP + ng)) * 6 + kb) * 512 + l8;
    const ushort* fl = xfl + (((size_t)(b * NGRP + ng)) * 6 + kb) * 512 + l8;
    s8v xh[3], xl[3];
#pragma unroll
    for (int kk = 0; kk < 3; ++kk) {
        xh[kk] = *(const s8v*)(fh + kk * 512);
        xl[kk] = *(const s8v*)(fl + kk * 512);
    }

    for (int ogg = 0; ogg < 6; ++ogg) {
        int ob = g * 6 + ogg;                  // og_block: rows ob*16..+15
        const ushort* ph = wfh + ((size_t)ob * 3) * 512 + l8;   // W k-dim is 0..95 always
        const ushort* pl = wfl + ((size_t)ob * 3) * 512 + l8;
        f4v acc = {0.f, 0.f, 0.f, 0.f};
#pragma unroll
        for (int kk = 0; kk < 3; ++kk) {
            s8v wh = *(const s8v*)(ph + kk * 512);
            s8v wl = *(const s8v*)(pl + kk * 512);
            acc = __builtin_amdgcn_mfma_f32_16x16x32_bf16(xh[kk], wh, acc, 0, 0, 0);
            acc = __builtin_amdgcn_mfma_f32_16x16x32_bf16(xh[kk], wl, acc, 0, 0, 0);
            acc = __builtin_amdgcn_mfma_f32_16x16x32_bf16(xl[kk], wh, acc, 0, 0, 0);
        }
        int row = g * 96 + ogg * 16 + m16;
        if (g < 2) {
            float bv = bias[row];
#pragma unroll
            for (int r = 0; r < 4; ++r) {
                int n = ng * 16 + h * 4 + r;
                out[((size_t)b * OUTC + row) * NPIX + n] = gelu_fast(acc[r] + bv);
            }
        } else {
            int r2 = (g - 2) * 96 + ogg * 16 + m16;
#pragma unroll
            for (int r = 0; r < 4; ++r) {
                int n = ng * 16 + h * 4 + r;
                tbuf[((size_t)b * 192 + r2) * NPIX + n] = acc[r];
            }
        }
    }
}

// ---------------- K4: groups 2/3, 8 channels per block (nnidx staged once) ----------------
// gelu unimodal: max over set = max(gelu(umin), gelu(umax))
__global__ __launch_bounds__(256) void k4_gather(const float* __restrict__ tbuf,
                                                 const int* __restrict__ nnidx,
                                                 const float* __restrict__ bias,
                                                 float* __restrict__ out) {
    __shared__ float trow[NPIX];
    __shared__ int nn[NPIX * KNN];
    int wg = blockIdx.x;                       // 768 = 8 xcd * (4 b * 24 oct)
    int b   = (wg & 7) * 4 + (wg >> 3) / 24;
    int oct = (wg >> 3) % 24;
    int t = threadIdx.x;
    const int4* nb4 = (const int4*)(nnidx + (size_t)b * NPIX * KNN);
    for (int i = t; i < NPIX * KNN / 4; i += 256) ((int4*)nn)[i] = nb4[i];

    for (int oo = 0; oo < 8; ++oo) {
        int og2 = oct * 8 + oo;
        const float4* tr4 = (const float4*)(tbuf + ((size_t)b * 192 + og2) * NPIX);
        for (int i = t; i < NPIX / 4; i += 256) ((float4*)trow)[i] = tr4[i];
        __syncthreads();
        float bv = bias[192 + og2];
        float* orow = out + ((size_t)b * OUTC + 192 + og2) * NPIX;
        for (int n = t; n < NPIX; n += 256) {
            float ti = trow[n];
            const int* ip = nn + n * KNN;
            float umin = 3.4e38f, umax = -3.4e38f;
#pragma unroll
            for (int k = 0; k < KNN; ++k) {
                int j = ip[k];
                float u = trow[j] - ti + bv;
                umin = fminf(umin, u);
                umax = fmaxf(umax, u);
            }
            orow[n] = fmaxf(gelu_fast(umin), gelu_fast(umax));
        }
        __syncthreads();                       // before next trow overwrite
    }
}

extern "C" void kernel_launch(void* const* d_in, const int* in_sizes, int n_in,
                              void* d_out, int out_size, void* d_ws, size_t ws_size,
                              hipStream_t stream) {
    const float* x    = (const float*)d_in[0];
    const float* w    = (const float*)d_in[1];
    const float* bias = (const float*)d_in[2];
    float* out = (float*)d_out;
    char* ws = (char*)d_ws;

    ushort* xfh   = (ushort*)(ws);
    ushort* xfl   = (ushort*)(ws + XFH_BYTES);
    float2* pair  = (float2*)(ws + XFH_BYTES + XFL_BYTES);
    int*    nnidx = (int*)   (ws + XFH_BYTES + XFL_BYTES + PAIR_BYTES);
    float*  tbuf  = (float*) (ws + XFH_BYTES + XFL_BYTES + PAIR_BYTES + IDX_BYTES);
    ushort* wfh   = (ushort*)(ws + XFH_BYTES + XFL_BYTES + PAIR_BYTES + IDX_BYTES + TBUF_BYTES);
    ushort* wfl   = (ushort*)(ws + XFH_BYTES + XFL_BYTES + PAIR_BYTES + IDX_BYTES + TBUF_BYTES + WF_BYTES);

    k0_wfrag<<<dim3(72), 64, 0, stream>>>(w, wfh, wfl);
    k1_normalize<<<dim3(13, BSZ), 256, 0, stream>>>(x, xfh, xfl, pair);
    k2_knn<<<dim3(1568), 128, 0, stream>>>(xfh, xfl, (const float*)pair, nnidx);
    k3_proj<<<dim3(1568), 256, 0, stream>>>(xfh, xfl, wfh, wfl, bias, out, tbuf);
    k4_gather<<<dim3(768), 256, 0, stream>>>(tbuf, nnidx, bias, out);
}

// Round 20
// 124.847 us; speedup vs baseline: 1.9842x; 1.0693x over previous
//
#include <hip/hip_runtime.h>
#include <math.h>

#define BSZ 32
#define CCH 192
#define NPIX 784
#define NP 896          // buffer stride (56 groups); only 49 real groups used
#define NGRP 56
#define NGU 49          // 784 = 49 * 16 exactly: no pad candidates
#define OUTC 384
#define KNN 9

typedef short s8v __attribute__((ext_vector_type(8)));
typedef float f4v __attribute__((ext_vector_type(4)));

// ---------------- ws layout ----------------
#define XFH_BYTES ((size_t)BSZ * NGRP * 6 * 64 * 8 * 2)   // 11,010,048
#define XFL_BYTES XFH_BYTES
#define PAIR_BYTES ((size_t)BSZ * NP * 8)                 //    229,376
#define IDX_BYTES ((size_t)BSZ * NPIX * KNN * 4)          //    903,168
#define TBUF_BYTES ((size_t)BSZ * 192 * NPIX * 4)         // 19,267,584
#define WF_BYTES ((size_t)24 * 3 * 64 * 8 * 2)            //     73,728 per buffer

__device__ __forceinline__ ushort bf16_rne(float f) {
    uint u = __float_as_uint(f);
    uint r = (u + 0x7fffu + ((u >> 16) & 1u)) >> 16;
    return (ushort)r;
}
__device__ __forceinline__ float bf16f(ushort h) { return __uint_as_float(((uint)h) << 16); }

// Abramowitz-Stegun 7.1.26 erf (|eps| <= 1.5e-7) -> exact-gelu within fp32 noise
__device__ __forceinline__ float gelu_fast(float u) {
    float x = u * 0.70710678118654752440f;
    float ax = fabsf(x);
    float t = __builtin_amdgcn_rcpf(fmaf(0.3275911f, ax, 1.0f));
    float p = t * fmaf(t, fmaf(t, fmaf(t, fmaf(t, 1.061405429f, -1.453152027f),
                                       1.421413741f), -0.284496736f), 0.254829592f);
    float e = __expf(-ax * ax);
    float erf_ax = fmaf(-p, e, 1.0f);
    float erfx = copysignf(erf_ax, x);
    return 0.5f * u * (1.0f + erfx);
}

// ---------------- K0: W -> bf16 hi/lo MFMA B-fragments (once). W rows = 96 ch = 3 kc chunks ----------------
__global__ __launch_bounds__(64) void k0_wfrag(const float* __restrict__ w,
                                               ushort* __restrict__ wfh,
                                               ushort* __restrict__ wfl) {
    int c2 = blockIdx.x;        // 0..71 : ob(24) * 3 + kc
    int l = threadIdx.x;
    int ob = c2 / 3, kc = c2 - ob * 3;
    int row = ob * 16 + (l & 15);
    int k0c = kc * 32 + (l >> 4) * 8;          // 0..95: within-row channel index
    const float* wr = w + row * 96 + k0c;
    s8v hv, lv;
#pragma unroll
    for (int k = 0; k < 8; ++k) {
        float v = wr[k];
        ushort h = bf16_rne(v);
        hv[k] = (short)h;
        lv[k] = (short)bf16_rne(v - bf16f(h));
    }
    *(s8v*)(wfh + ((size_t)c2 * 64 + l) * 8) = hv;
    *(s8v*)(wfl + ((size_t)c2 * 64 + l) * 8) = lv;
}

// ---------------- K1: coalesced load -> RAW bf16 hi/lo fragments + {sq,inv} ----------------
__global__ __launch_bounds__(256) void k1_normalize(const float* __restrict__ x,
                                                    ushort* __restrict__ xfh,
                                                    ushort* __restrict__ xfl,
                                                    float2* __restrict__ pair) {
    __shared__ float xs[CCH][65];
    int b = blockIdx.y;
    int n0 = blockIdx.x * 64;
    int t = threadIdx.x;
    const float* xb = x + (size_t)b * CCH * NPIX;

    for (int i = t; i < CCH * 64; i += 256) {
        int c = i >> 6, j = i & 63, n = n0 + j;
        xs[c][j] = (n < NPIX) ? xb[c * NPIX + n] : 0.f;
    }
    __syncthreads();

    {
        int j = t >> 2, part = t & 3;
        float ss = 0.f;
        for (int k = 0; k < 48; ++k) { float v = xs[part * 48 + k][j]; ss = fmaf(v, v, ss); }
        ss += __shfl_xor(ss, 1);
        ss += __shfl_xor(ss, 2);
        float inv = 1.0f / fmaxf(sqrtf(ss), 1e-12f);
        float s2 = 0.f;
        for (int k = 0; k < 48; ++k) {
            float v = xs[part * 48 + k][j] * inv;
            s2 = fmaf(v, v, s2);
        }
        s2 += __shfl_xor(s2, 1);
        s2 += __shfl_xor(s2, 2);
        if (part == 0) {
            int n = n0 + j;
            pair[b * NP + n] = (n < NPIX) ? make_float2(s2, inv) : make_float2(1e30f, 0.f);
        }
    }

#pragma unroll
    for (int i = 0; i < 6; ++i) {
        int ch = t + i * 256;
        int g = ch / 384, rem = ch - g * 384;
        int kc = rem >> 6, l = rem & 63;
        int nl = g * 16 + (l & 15);
        int c0 = kc * 32 + (l >> 4) * 8;
        s8v hv, lv;
#pragma unroll
        for (int k = 0; k < 8; ++k) {
            float v = xs[c0 + k][nl];
            ushort h = bf16_rne(v);
            hv[k] = (short)h;
            lv[k] = (short)bf16_rne(v - bf16f(h));
        }
        size_t doff = (((size_t)(b * NGRP + (n0 >> 4) + g)) * 6 + kc) * 512 + (size_t)l * 8;
        *(s8v*)(xfh + doff) = hv;
        *(s8v*)(xfl + doff) = lv;
    }
}

// ---------------- K23: MFMA knn (LDS queries) + fused projection epilogue ----------------
__device__ __forceinline__ bool lt_pair(float v, int id, float dv, int di) {
    return (v < dv) || (v == dv && id < di);
}
// branchless strict-< sorted insert (ascending per-lane id stream -> lax.top_k tie order)
__device__ __forceinline__ void ins9b(float (&d)[KNN], int (&ii)[KNN], float v, int id) {
    bool c[KNN];
#pragma unroll
    for (int p = 0; p < KNN; ++p) c[p] = v < d[p];
    float nd[KNN]; int ni[KNN];
    nd[0] = c[0] ? v : d[0];
    ni[0] = c[0] ? id : ii[0];
#pragma unroll
    for (int p = 1; p < KNN; ++p) {
        nd[p] = c[p - 1] ? d[p - 1] : (c[p] ? v : d[p]);
        ni[p] = c[p - 1] ? ii[p - 1] : (c[p] ? id : ii[p]);
    }
#pragma unroll
    for (int p = 0; p < KNN; ++p) { d[p] = nd[p]; ii[p] = ni[p]; }
}

__global__ __launch_bounds__(128) void k23_knn_proj(const ushort* __restrict__ xfh,
                                                    const ushort* __restrict__ xfl,
                                                    const float* __restrict__ pair,
                                                    const ushort* __restrict__ wfh,
                                                    const ushort* __restrict__ wfl,
                                                    const float* __restrict__ bias,
                                                    int* __restrict__ nnidx,
                                                    float* __restrict__ out,
                                                    float* __restrict__ tbuf) {
    __shared__ ushort qlds[12 * 512];          // 12 KB: chunks 0..5 = hi, 6..11 = lo
    __shared__ float dls[2][64][KNN];
    __shared__ int   ils[2][64][KNN];
    int wg = blockIdx.x;                       // 1568 = 8 xcd * (4 b * 49 qt)
    int b  = (wg & 7) * 4 + (wg >> 3) / 49;
    int qt = (wg >> 3) % 49;
    int t = threadIdx.x, w = t >> 6, l = t & 63;
    int lk = l >> 4;
    const ushort* fh = xfh + (size_t)b * NGRP * 3072;
    const ushort* fl = xfl + (size_t)b * NGRP * 3072;
    const float2* pb = (const float2*)(pair + (size_t)b * NP * 2);
    int l8 = l * 8;

    // stage query fragments (16 queries of group qt) into LDS once
    {
        const ushort* qh_g = fh + (size_t)qt * 3072;
        const ushort* ql_g = fl + (size_t)qt * 3072;
        for (int i = t; i < 768; i += 128) {   // 768 chunks of 8 ushorts = 12 KB
            int half = i / 384;
            int off = (i - half * 384) * 8;
            s8v v = *(const s8v*)((half ? ql_g : qh_g) + off);
            *(s8v*)(qlds + half * 3072 + off) = v;
        }
    }
    float c2q = -2.f * pb[qt * 16 + (l & 15)].y;
    __syncthreads();

    float d9[KNN]; int i9[KNN];
#pragma unroll
    for (int r = 0; r < KNN; ++r) { d9[r] = 3.4e38f; i9[r] = 0x7fffffff; }

    const ushort* qp = qlds + l8;              // per-lane LDS base; kc via imm offsets

    // wave 0: groups 0..23, wave 1: groups 24..48 (784 real candidates, no pads)
    int g0 = w ? 24 : 0, g1 = w ? NGU : 24;
#pragma unroll 2
    for (int cg = g0; cg < g1; ++cg) {
        const ushort* ch = fh + (size_t)cg * 3072 + l8;
        const ushort* cl = fl + (size_t)cg * 3072 + l8;
        f4v aH  = {0.f, 0.f, 0.f, 0.f};
        f4v aX1 = {0.f, 0.f, 0.f, 0.f};
        f4v aX2 = {0.f, 0.f, 0.f, 0.f};
        f4v aX3 = {0.f, 0.f, 0.f, 0.f};
#pragma unroll
        for (int kc = 0; kc < 6; ++kc) {
            s8v vh = *(const s8v*)(ch + kc * 512);
            s8v vl = *(const s8v*)(cl + kc * 512);
            s8v qh = *(const s8v*)(qp + kc * 512);          // ds_read_b128
            s8v ql = *(const s8v*)(qp + 3072 + kc * 512);   // ds_read_b128
            aH  = __builtin_amdgcn_mfma_f32_16x16x32_bf16(vh, qh, aH,  0, 0, 0);
            aX1 = __builtin_amdgcn_mfma_f32_16x16x32_bf16(vl, qh, aX1, 0, 0, 0);
            aX2 = __builtin_amdgcn_mfma_f32_16x16x32_bf16(vh, ql, aX2, 0, 0, 0);
            aX3 = __builtin_amdgcn_mfma_f32_16x16x32_bf16(vl, ql, aX3, 0, 0, 0);
        }
        float4 pA = *(const float4*)(pb + (size_t)(cg * 16 + lk * 4));
        float4 pB = *(const float4*)(pb + (size_t)(cg * 16 + lk * 4) + 2);
        float sqn_[4] = {pA.x, pA.z, pB.x, pB.z};
        float inv_[4] = {pA.y, pA.w, pB.y, pB.w};
#pragma unroll
        for (int r = 0; r < 4; ++r) {
            float v = fmaf(c2q * inv_[r], aH[r] + aX1[r] + aX2[r] + aX3[r], sqn_[r]);
            ins9b(d9, i9, v, cg * 16 + lk * 4 + r);
        }
    }

    // dump 8 sorted lists per query (2 waves x 4 lk-groups) and merge
#pragma unroll
    for (int r = 0; r < KNN; ++r) { dls[w][l][r] = d9[r]; ils[w][l][r] = i9[r]; }
    __syncthreads();
    if (t < 16) {
        int q = qt * 16 + t;
        int pk[8] = {0, 0, 0, 0, 0, 0, 0, 0};
        int* op = nnidx + ((size_t)b * NPIX + q) * KNN;
        for (int r = 0; r < KNN; ++r) {
            float best = 3.4e38f; int bi = 0x7fffffff; int bk = 0;
#pragma unroll
            for (int m = 0; m < 8; ++m) {
                int ww = m >> 2, kk = m & 3;
                int idx = pk[m] < KNN ? pk[m] : KNN - 1;
                float v = dls[ww][kk * 16 + t][idx];
                int ii = ils[ww][kk * 16 + t][idx];
                if (pk[m] < KNN && lt_pair(v, ii, best, bi)) { best = v; bi = ii; bk = m; }
            }
            op[r] = bi;
#pragma unroll
            for (int m = 0; m < 8; ++m) pk[m] += (m == bk) ? 1 : 0;
        }
    }

    // ---- fused projection (former k3) for node group qt: X frags already in qlds ----
    {
        int h = l >> 4, m16 = l & 15;
        for (int gg = 0; gg < 2; ++gg) {
            int g = w * 2 + gg;                // wave0: g 0,1 (out); wave1: g 2,3 (tbuf)
            int kb = (g & 1) * 3;              // X-side channel-half selector
            s8v xh[3], xl[3];
#pragma unroll
            for (int kk = 0; kk < 3; ++kk) {
                xh[kk] = *(const s8v*)(qlds + (kb + kk) * 512 + l8);
                xl[kk] = *(const s8v*)(qlds + 3072 + (kb + kk) * 512 + l8);
            }
            for (int ogg = 0; ogg < 6; ++ogg) {
                int ob = g * 6 + ogg;          // og_block: rows ob*16..+15
                const ushort* ph = wfh + ((size_t)ob * 3) * 512 + l8;
                const ushort* pl = wfl + ((size_t)ob * 3) * 512 + l8;
                f4v acc = {0.f, 0.f, 0.f, 0.f};
#pragma unroll
                for (int kk = 0; kk < 3; ++kk) {
                    s8v wh_ = *(const s8v*)(ph + kk * 512);
                    s8v wl_ = *(const s8v*)(pl + kk * 512);
                    acc = __builtin_amdgcn_mfma_f32_16x16x32_bf16(xh[kk], wh_, acc, 0, 0, 0);
                    acc = __builtin_amdgcn_mfma_f32_16x16x32_bf16(xh[kk], wl_, acc, 0, 0, 0);
                    acc = __builtin_amdgcn_mfma_f32_16x16x32_bf16(xl[kk], wh_, acc, 0, 0, 0);
                }
                int row = g * 96 + ogg * 16 + m16;
                if (g < 2) {
                    float bv = bias[row];
#pragma unroll
                    for (int r = 0; r < 4; ++r) {
                        int n = qt * 16 + h * 4 + r;
                        out[((size_t)b * OUTC + row) * NPIX + n] = gelu_fast(acc[r] + bv);
                    }
                } else {
                    int r2 = (g - 2) * 96 + ogg * 16 + m16;
#pragma unroll
                    for (int r = 0; r < 4; ++r) {
                        int n = qt * 16 + h * 4 + r;
                        tbuf[((size_t)b * 192 + r2) * NPIX + n] = acc[r];
                    }
                }
            }
        }
    }
}

// ---------------- K4: groups 2/3, 8 channels per block (nnidx staged once) ----------------
// gelu unimodal: max over set = max(gelu(umin), gelu(umax))
__global__ __launch_bounds__(256) void k4_gather(const float* __restrict__ tbuf,
                                                 const int* __restrict__ nnidx,
                                                 const float* __restrict__ bias,
                                                 float* __restrict__ out) {
    __shared__ float trow[NPIX];
    __shared__ int nn[NPIX * KNN];
    int wg = blockIdx.x;                       // 768 = 8 xcd * (4 b * 24 oct)
    int b   = (wg & 7) * 4 + (wg >> 3) / 24;
    int oct = (wg >> 3) % 24;
    int t = threadIdx.x;
    const int4* nb4 = (const int4*)(nnidx + (size_t)b * NPIX * KNN);
    for (int i = t; i < NPIX * KNN / 4; i += 256) ((int4*)nn)[i] = nb4[i];

    for (int oo = 0; oo < 8; ++oo) {
        int og2 = oct * 8 + oo;
        const float4* tr4 = (const float4*)(tbuf + ((size_t)b * 192 + og2) * NPIX);
        for (int i = t; i < NPIX / 4; i += 256) ((float4*)trow)[i] = tr4[i];
        __syncthreads();
        float bv = bias[192 + og2];
        float* orow = out + ((size_t)b * OUTC + 192 + og2) * NPIX;
        for (int n = t; n < NPIX; n += 256) {
            float ti = trow[n];
            const int* ip = nn + n * KNN;
            float umin = 3.4e38f, umax = -3.4e38f;
#pragma unroll
            for (int k = 0; k < KNN; ++k) {
                int j = ip[k];
                float u = trow[j] - ti + bv;
                umin = fminf(umin, u);
                umax = fmaxf(umax, u);
            }
            orow[n] = fmaxf(gelu_fast(umin), gelu_fast(umax));
        }
        __syncthreads();                       // before next trow overwrite
    }
}

extern "C" void kernel_launch(void* const* d_in, const int* in_sizes, int n_in,
                              void* d_out, int out_size, void* d_ws, size_t ws_size,
                              hipStream_t stream) {
    const float* x    = (const float*)d_in[0];
    const float* w    = (const float*)d_in[1];
    const float* bias = (const float*)d_in[2];
    float* out = (float*)d_out;
    char* ws = (char*)d_ws;

    ushort* xfh   = (ushort*)(ws);
    ushort* xfl   = (ushort*)(ws + XFH_BYTES);
    float2* pair  = (float2*)(ws + XFH_BYTES + XFL_BYTES);
    int*    nnidx = (int*)   (ws + XFH_BYTES + XFL_BYTES + PAIR_BYTES);
    float*  tbuf  = (float*) (ws + XFH_BYTES + XFL_BYTES + PAIR_BYTES + IDX_BYTES);
    ushort* wfh   = (ushort*)(ws + XFH_BYTES + XFL_BYTES + PAIR_BYTES + IDX_BYTES + TBUF_BYTES);
    ushort* wfl   = (ushort*)(ws + XFH_BYTES + XFL_BYTES + PAIR_BYTES + IDX_BYTES + TBUF_BYTES + WF_BYTES);

    k0_wfrag<<<dim3(72), 64, 0, stream>>>(w, wfh, wfl);
    k1_normalize<<<dim3(13, BSZ), 256, 0, stream>>>(x, xfh, xfl, pair);
    k23_knn_proj<<<dim3(1568), 128, 0, stream>>>(xfh, xfl, (const float*)pair,
                                                 wfh, wfl, bias, nnidx, out, tbuf);
    k4_gather<<<dim3(768), 256, 0, stream>>>(tbuf, nnidx, bias, out);
}

// Round 21
// 121.479 us; speedup vs baseline: 2.0392x; 1.0277x over previous
//
#include <hip/hip_runtime.h>
#include <math.h>

#define BSZ 32
#define CCH 192
#define NPIX 784
#define NP 896          // buffer stride (56 groups); only 49 real groups used
#define NGRP 56
#define NGU 49          // 784 = 49 * 16 exactly: no pad candidates
#define OUTC 384
#define KNN 9

typedef short s8v __attribute__((ext_vector_type(8)));
typedef float f4v __attribute__((ext_vector_type(4)));

// ---------------- ws layout ----------------
#define XFH_BYTES ((size_t)BSZ * NGRP * 6 * 64 * 8 * 2)   // 11,010,048
#define XFL_BYTES XFH_BYTES
#define PAIR_BYTES ((size_t)BSZ * NP * 8)                 //    229,376
#define IDX_BYTES ((size_t)BSZ * NPIX * KNN * 4)          //    903,168
#define TBUF_BYTES ((size_t)BSZ * 192 * NPIX * 4)         // 19,267,584
#define WF_BYTES ((size_t)24 * 3 * 64 * 8 * 2)            //     73,728 per buffer

__device__ __forceinline__ ushort bf16_rne(float f) {
    uint u = __float_as_uint(f);
    uint r = (u + 0x7fffu + ((u >> 16) & 1u)) >> 16;
    return (ushort)r;
}
__device__ __forceinline__ float bf16f(ushort h) { return __uint_as_float(((uint)h) << 16); }

// Abramowitz-Stegun 7.1.26 erf (|eps| <= 1.5e-7) -> exact-gelu within fp32 noise
__device__ __forceinline__ float gelu_fast(float u) {
    float x = u * 0.70710678118654752440f;
    float ax = fabsf(x);
    float t = __builtin_amdgcn_rcpf(fmaf(0.3275911f, ax, 1.0f));
    float p = t * fmaf(t, fmaf(t, fmaf(t, fmaf(t, 1.061405429f, -1.453152027f),
                                       1.421413741f), -0.284496736f), 0.254829592f);
    float e = __expf(-ax * ax);
    float erf_ax = fmaf(-p, e, 1.0f);
    float erfx = copysignf(erf_ax, x);
    return 0.5f * u * (1.0f + erfx);
}

// ---------------- K0: W -> bf16 hi/lo MFMA B-fragments (once). W rows = 96 ch = 3 kc chunks ----------------
__global__ __launch_bounds__(64) void k0_wfrag(const float* __restrict__ w,
                                               ushort* __restrict__ wfh,
                                               ushort* __restrict__ wfl) {
    int c2 = blockIdx.x;        // 0..71 : ob(24) * 3 + kc
    int l = threadIdx.x;
    int ob = c2 / 3, kc = c2 - ob * 3;
    int row = ob * 16 + (l & 15);
    int k0c = kc * 32 + (l >> 4) * 8;          // 0..95: within-row channel index
    const float* wr = w + row * 96 + k0c;
    s8v hv, lv;
#pragma unroll
    for (int k = 0; k < 8; ++k) {
        float v = wr[k];
        ushort h = bf16_rne(v);
        hv[k] = (short)h;
        lv[k] = (short)bf16_rne(v - bf16f(h));
    }
    *(s8v*)(wfh + ((size_t)c2 * 64 + l) * 8) = hv;
    *(s8v*)(wfl + ((size_t)c2 * 64 + l) * 8) = lv;
}

// ---------------- K1: coalesced load -> RAW bf16 hi/lo fragments + {sq,inv} ----------------
__global__ __launch_bounds__(256) void k1_normalize(const float* __restrict__ x,
                                                    ushort* __restrict__ xfh,
                                                    ushort* __restrict__ xfl,
                                                    float2* __restrict__ pair) {
    __shared__ float xs[CCH][65];
    int b = blockIdx.y;
    int n0 = blockIdx.x * 64;
    int t = threadIdx.x;
    const float* xb = x + (size_t)b * CCH * NPIX;

    for (int i = t; i < CCH * 64; i += 256) {
        int c = i >> 6, j = i & 63, n = n0 + j;
        xs[c][j] = (n < NPIX) ? xb[c * NPIX + n] : 0.f;
    }
    __syncthreads();

    {
        int j = t >> 2, part = t & 3;
        float ss = 0.f;
        for (int k = 0; k < 48; ++k) { float v = xs[part * 48 + k][j]; ss = fmaf(v, v, ss); }
        ss += __shfl_xor(ss, 1);
        ss += __shfl_xor(ss, 2);
        float inv = 1.0f / fmaxf(sqrtf(ss), 1e-12f);
        float s2 = 0.f;
        for (int k = 0; k < 48; ++k) {
            float v = xs[part * 48 + k][j] * inv;
            s2 = fmaf(v, v, s2);
        }
        s2 += __shfl_xor(s2, 1);
        s2 += __shfl_xor(s2, 2);
        if (part == 0) {
            int n = n0 + j;
            pair[b * NP + n] = (n < NPIX) ? make_float2(s2, inv) : make_float2(1e30f, 0.f);
        }
    }

#pragma unroll
    for (int i = 0; i < 6; ++i) {
        int ch = t + i * 256;
        int g = ch / 384, rem = ch - g * 384;
        int kc = rem >> 6, l = rem & 63;
        int nl = g * 16 + (l & 15);
        int c0 = kc * 32 + (l >> 4) * 8;
        s8v hv, lv;
#pragma unroll
        for (int k = 0; k < 8; ++k) {
            float v = xs[c0 + k][nl];
            ushort h = bf16_rne(v);
            hv[k] = (short)h;
            lv[k] = (short)bf16_rne(v - bf16f(h));
        }
        size_t doff = (((size_t)(b * NGRP + (n0 >> 4) + g)) * 6 + kc) * 512 + (size_t)l * 8;
        *(s8v*)(xfh + doff) = hv;
        *(s8v*)(xfl + doff) = lv;
    }
}

// ---------------- K23: MFMA knn (LDS queries) + fused projection epilogue ----------------
__device__ __forceinline__ bool lt_pair(float v, int id, float dv, int di) {
    return (v < dv) || (v == dv && id < di);
}
// branchless strict-< sorted insert (ascending per-lane id stream -> lax.top_k tie order)
__device__ __forceinline__ void ins9b(float (&d)[KNN], int (&ii)[KNN], float v, int id) {
    bool c[KNN];
#pragma unroll
    for (int p = 0; p < KNN; ++p) c[p] = v < d[p];
    float nd[KNN]; int ni[KNN];
    nd[0] = c[0] ? v : d[0];
    ni[0] = c[0] ? id : ii[0];
#pragma unroll
    for (int p = 1; p < KNN; ++p) {
        nd[p] = c[p - 1] ? d[p - 1] : (c[p] ? v : d[p]);
        ni[p] = c[p - 1] ? ii[p - 1] : (c[p] ? id : ii[p]);
    }
#pragma unroll
    for (int p = 0; p < KNN; ++p) { d[p] = nd[p]; ii[p] = ni[p]; }
}

__global__ __launch_bounds__(128) void k23_knn_proj(const ushort* __restrict__ xfh,
                                                    const ushort* __restrict__ xfl,
                                                    const float* __restrict__ pair,
                                                    const ushort* __restrict__ wfh,
                                                    const ushort* __restrict__ wfl,
                                                    const float* __restrict__ bias,
                                                    int* __restrict__ nnidx,
                                                    float* __restrict__ out,
                                                    float* __restrict__ tbuf) {
    __shared__ ushort qlds[12 * 512];          // 12 KB: chunks 0..5 = hi, 6..11 = lo
    __shared__ float dls[2][64][KNN];
    __shared__ int   ils[2][64][KNN];
    int wg = blockIdx.x;                       // 1568 = 8 xcd * (4 b * 49 qt)
    int b  = (wg & 7) * 4 + (wg >> 3) / 49;
    int qt = (wg >> 3) % 49;
    int t = threadIdx.x, w = t >> 6, l = t & 63;
    int lk = l >> 4;
    const ushort* fh = xfh + (size_t)b * NGRP * 3072;
    const ushort* fl = xfl + (size_t)b * NGRP * 3072;
    const float2* pb = (const float2*)(pair + (size_t)b * NP * 2);
    int l8 = l * 8;

    // stage query fragments (16 queries of group qt) into LDS once
    {
        const ushort* qh_g = fh + (size_t)qt * 3072;
        const ushort* ql_g = fl + (size_t)qt * 3072;
        for (int i = t; i < 768; i += 128) {   // 768 chunks of 8 ushorts = 12 KB
            int half = i / 384;
            int off = (i - half * 384) * 8;
            s8v v = *(const s8v*)((half ? ql_g : qh_g) + off);
            *(s8v*)(qlds + half * 3072 + off) = v;
        }
    }
    float c2q = -2.f * pb[qt * 16 + (l & 15)].y;
    __syncthreads();

    float d9[KNN]; int i9[KNN];
#pragma unroll
    for (int r = 0; r < KNN; ++r) { d9[r] = 3.4e38f; i9[r] = 0x7fffffff; }

    const ushort* qp = qlds + l8;              // per-lane LDS base; kc via imm offsets

    // wave 0: groups 0..23, wave 1: groups 24..48 (784 real candidates, no pads)
    int g0 = w ? 24 : 0, g1 = w ? NGU : 24;
#pragma unroll 2
    for (int cg = g0; cg < g1; ++cg) {
        const ushort* ch = fh + (size_t)cg * 3072 + l8;
        const ushort* cl = fl + (size_t)cg * 3072 + l8;
        f4v aH  = {0.f, 0.f, 0.f, 0.f};
        f4v aX1 = {0.f, 0.f, 0.f, 0.f};
        f4v aX2 = {0.f, 0.f, 0.f, 0.f};
        f4v aX3 = {0.f, 0.f, 0.f, 0.f};
        __builtin_amdgcn_s_setprio(1);         // waves run barrier-free: favor MFMA issuer
#pragma unroll
        for (int kc = 0; kc < 6; ++kc) {
            s8v vh = *(const s8v*)(ch + kc * 512);
            s8v vl = *(const s8v*)(cl + kc * 512);
            s8v qh = *(const s8v*)(qp + kc * 512);          // ds_read_b128
            s8v ql = *(const s8v*)(qp + 3072 + kc * 512);   // ds_read_b128
            aH  = __builtin_amdgcn_mfma_f32_16x16x32_bf16(vh, qh, aH,  0, 0, 0);
            aX1 = __builtin_amdgcn_mfma_f32_16x16x32_bf16(vl, qh, aX1, 0, 0, 0);
            aX2 = __builtin_amdgcn_mfma_f32_16x16x32_bf16(vh, ql, aX2, 0, 0, 0);
            aX3 = __builtin_amdgcn_mfma_f32_16x16x32_bf16(vl, ql, aX3, 0, 0, 0);
        }
        __builtin_amdgcn_s_setprio(0);
        float4 pA = *(const float4*)(pb + (size_t)(cg * 16 + lk * 4));
        float4 pB = *(const float4*)(pb + (size_t)(cg * 16 + lk * 4) + 2);
        float sqn_[4] = {pA.x, pA.z, pB.x, pB.z};
        float inv_[4] = {pA.y, pA.w, pB.y, pB.w};
#pragma unroll
        for (int r = 0; r < 4; ++r) {
            float v = fmaf(c2q * inv_[r], aH[r] + aX1[r] + aX2[r] + aX3[r], sqn_[r]);
            ins9b(d9, i9, v, cg * 16 + lk * 4 + r);
        }
    }

    // dump 8 sorted lists per query (2 waves x 4 lk-groups) and merge
#pragma unroll
    for (int r = 0; r < KNN; ++r) { dls[w][l][r] = d9[r]; ils[w][l][r] = i9[r]; }
    __syncthreads();
    if (t < 16) {
        int q = qt * 16 + t;
        int pk[8] = {0, 0, 0, 0, 0, 0, 0, 0};
        int* op = nnidx + ((size_t)b * NPIX + q) * KNN;
        for (int r = 0; r < KNN; ++r) {
            float best = 3.4e38f; int bi = 0x7fffffff; int bk = 0;
#pragma unroll
            for (int m = 0; m < 8; ++m) {
                int ww = m >> 2, kk = m & 3;
                int idx = pk[m] < KNN ? pk[m] : KNN - 1;
                float v = dls[ww][kk * 16 + t][idx];
                int ii = ils[ww][kk * 16 + t][idx];
                if (pk[m] < KNN && lt_pair(v, ii, best, bi)) { best = v; bi = ii; bk = m; }
            }
            op[r] = bi;
#pragma unroll
            for (int m = 0; m < 8; ++m) pk[m] += (m == bk) ? 1 : 0;
        }
    }

    // ---- fused projection (former k3) for node group qt: X frags already in qlds ----
    {
        int h = l >> 4, m16 = l & 15;
        for (int gg = 0; gg < 2; ++gg) {
            int g = w * 2 + gg;                // wave0: g 0,1 (out); wave1: g 2,3 (tbuf)
            int kb = (g & 1) * 3;              // X-side channel-half selector
            s8v xh[3], xl[3];
#pragma unroll
            for (int kk = 0; kk < 3; ++kk) {
                xh[kk] = *(const s8v*)(qlds + (kb + kk) * 512 + l8);
                xl[kk] = *(const s8v*)(qlds + 3072 + (kb + kk) * 512 + l8);
            }
            for (int ogg = 0; ogg < 6; ++ogg) {
                int ob = g * 6 + ogg;          // og_block: rows ob*16..+15
                const ushort* ph = wfh + ((size_t)ob * 3) * 512 + l8;
                const ushort* pl = wfl + ((size_t)ob * 3) * 512 + l8;
                f4v acc = {0.f, 0.f, 0.f, 0.f};
#pragma unroll
                for (int kk = 0; kk < 3; ++kk) {
                    s8v wh_ = *(const s8v*)(ph + kk * 512);
                    s8v wl_ = *(const s8v*)(pl + kk * 512);
                    acc = __builtin_amdgcn_mfma_f32_16x16x32_bf16(xh[kk], wh_, acc, 0, 0, 0);
                    acc = __builtin_amdgcn_mfma_f32_16x16x32_bf16(xh[kk], wl_, acc, 0, 0, 0);
                    acc = __builtin_amdgcn_mfma_f32_16x16x32_bf16(xl[kk], wh_, acc, 0, 0, 0);
                }
                int row = g * 96 + ogg * 16 + m16;
                if (g < 2) {
                    float bv = bias[row];
#pragma unroll
                    for (int r = 0; r < 4; ++r) {
                        int n = qt * 16 + h * 4 + r;
                        out[((size_t)b * OUTC + row) * NPIX + n] = gelu_fast(acc[r] + bv);
                    }
                } else {
                    int r2 = (g - 2) * 96 + ogg * 16 + m16;
#pragma unroll
                    for (int r = 0; r < 4; ++r) {
                        int n = qt * 16 + h * 4 + r;
                        tbuf[((size_t)b * 192 + r2) * NPIX + n] = acc[r];
                    }
                }
            }
        }
    }
}

// ---------------- K4: groups 2/3, 8 channels per block, nn lists in registers ----------------
// gelu unimodal: max over set = max(gelu(umin), gelu(umax))
__global__ __launch_bounds__(256) void k4_gather(const float* __restrict__ tbuf,
                                                 const int* __restrict__ nnidx,
                                                 const float* __restrict__ bias,
                                                 float* __restrict__ out) {
    __shared__ float trow[NPIX];
    int wg = blockIdx.x;                       // 768 = 8 xcd * (4 b * 24 oct)
    int b   = (wg & 7) * 4 + (wg >> 3) / 24;
    int oct = (wg >> 3) % 24;
    int t = threadIdx.x;

    // preload this thread's nn lists (nodes t, t+256, t+512, t+768 if <784)
    int nnr[4][KNN];
#pragma unroll
    for (int s = 0; s < 4; ++s) {
        int n = t + s * 256;
        if (n < NPIX) {
            const int* ip = nnidx + ((size_t)b * NPIX + n) * KNN;
#pragma unroll
            for (int k = 0; k < KNN; ++k) nnr[s][k] = ip[k];
        }
    }

    for (int oo = 0; oo < 8; ++oo) {
        int og2 = oct * 8 + oo;
        const float4* tr4 = (const float4*)(tbuf + ((size_t)b * 192 + og2) * NPIX);
        for (int i = t; i < NPIX / 4; i += 256) ((float4*)trow)[i] = tr4[i];
        __syncthreads();
        float bv = bias[192 + og2];
        float* orow = out + ((size_t)b * OUTC + 192 + og2) * NPIX;
#pragma unroll
        for (int s = 0; s < 4; ++s) {
            int n = t + s * 256;
            if (n < NPIX) {
                float ti = trow[n];
                float umin = 3.4e38f, umax = -3.4e38f;
#pragma unroll
                for (int k = 0; k < KNN; ++k) {
                    float u = trow[nnr[s][k]] - ti + bv;
                    umin = fminf(umin, u);
                    umax = fmaxf(umax, u);
                }
                orow[n] = fmaxf(gelu_fast(umin), gelu_fast(umax));
            }
        }
        __syncthreads();                       // before next trow overwrite
    }
}

extern "C" void kernel_launch(void* const* d_in, const int* in_sizes, int n_in,
                              void* d_out, int out_size, void* d_ws, size_t ws_size,
                              hipStream_t stream) {
    const float* x    = (const float*)d_in[0];
    const float* w    = (const float*)d_in[1];
    const float* bias = (const float*)d_in[2];
    float* out = (float*)d_out;
    char* ws = (char*)d_ws;

    ushort* xfh   = (ushort*)(ws);
    ushort* xfl   = (ushort*)(ws + XFH_BYTES);
    float2* pair  = (float2*)(ws + XFH_BYTES + XFL_BYTES);
    int*    nnidx = (int*)   (ws + XFH_BYTES + XFL_BYTES + PAIR_BYTES);
    float*  tbuf  = (float*) (ws + XFH_BYTES + XFL_BYTES + PAIR_BYTES + IDX_BYTES);
    ushort* wfh   = (ushort*)(ws + XFH_BYTES + XFL_BYTES + PAIR_BYTES + IDX_BYTES + TBUF_BYTES);
    ushort* wfl   = (ushort*)(ws + XFH_BYTES + XFL_BYTES + PAIR_BYTES + IDX_BYTES + TBUF_BYTES + WF_BYTES);

    k0_wfrag<<<dim3(72), 64, 0, stream>>>(w, wfh, wfl);
    k1_normalize<<<dim3(13, BSZ), 256, 0, stream>>>(x, xfh, xfl, pair);
    k23_knn_proj<<<dim3(1568), 128, 0, stream>>>(xfh, xfl, (const float*)pair,
                                                 wfh, wfl, bias, nnidx, out, tbuf);
    k4_gather<<<dim3(768), 256, 0, stream>>>(tbuf, nnidx, bias, out);
}